// Round 13
// baseline (602.543 us; speedup 1.0000x reference)
//
#include <hip/hip_runtime.h>
#include <hip/hip_bf16.h>

typedef __bf16 bf16_t;
typedef __attribute__((ext_vector_type(8))) __bf16 bf16x8;
typedef __attribute__((ext_vector_type(4))) float f32x4;

// ---------------- prep kernels (tiny, unchanged) ----------------
__global__ void prep_wvp(const float* __restrict__ Wv, const float* __restrict__ Wp,
                         const float* __restrict__ bp, const float* __restrict__ bv,
                         float* __restrict__ Wvp, float* __restrict__ bvp) {
  const int i = blockIdx.x;
  const int j = threadIdx.x;
  float a = 0.f;
  for (int d = 0; d < 512; ++d) a += Wv[i * 512 + d] * Wp[d * 256 + j];
  Wvp[i * 256 + j] = a;
  if (j == 0) {
    float b = 0.f;
    for (int d = 0; d < 512; ++d) b += Wv[i * 512 + d] * bp[d];
    bvp[i] = b + bv[i];
  }
}

// Packed-B layout (harness-verified rounds 4/7-12), N x K row-major source:
//   B[n][k] -> Bp[(((n>>4)*(K/32) + (k>>5))*64 + ((k>>3)&3)*16 + (n&15))*8 + (k&7)]
__global__ void prep_wc(const float* __restrict__ Wo, const float* __restrict__ bo,
                        const float* __restrict__ Wvp, const float* __restrict__ bvp,
                        bf16_t* __restrict__ Wc, float* __restrict__ bcomb) {
  const int o = blockIdx.x;
  const int j = threadIdx.x;
  float a = 0.f;
  for (int i = 0; i < 512; ++i) a += Wo[o * 512 + i] * Wvp[i * 256 + j];
  const int g = o >> 4, rr = o & 15, t = j >> 5, q = (j >> 3) & 3, e = j & 7;
  Wc[((((size_t)g * 8 + t) * 64) + q * 16 + rr) * 8 + e] = (bf16_t)a;  // S=8
  if (j == 0) {
    float b = 0.f;
    for (int i = 0; i < 512; ++i) b += Wo[o * 512 + i] * bvp[i];
    bcomb[o] = b + bo[o];
  }
}

__global__ void prep_cast(const float* __restrict__ W1, const float* __restrict__ W2,
                          bf16_t* __restrict__ W1b, bf16_t* __restrict__ W2b) {
  const int idx = (blockIdx.x * 256 + threadIdx.x) * 8;
  const float* s;
  bf16_t* d;
  if (idx < 524288) {  // W1: K=512, S=16
    const int o = idx >> 9, k = idx & 511;
    const int g = o >> 4, rr = o & 15, t = k >> 5, q = (k >> 3) & 3;
    s = W1 + idx;
    d = W1b + ((((size_t)g * 16 + t) * 64) + q * 16 + rr) * 8;
  } else {             // W2: K=1024, S=32
    const int i2 = idx - 524288;
    const int o = i2 >> 10, k = i2 & 1023;
    const int g = o >> 4, rr = o & 15, t = k >> 5, q = (k >> 3) & 3;
    s = W2 + i2;
    d = W2b + ((((size_t)g * 32 + t) * 64) + q * 16 + rr) * 8;
  }
  float4 u0 = *(const float4*)s;
  float4 u1 = *(const float4*)(s + 4);
  bf16x8 v;
  v[0] = (bf16_t)u0.x; v[1] = (bf16_t)u0.y; v[2] = (bf16_t)u0.z; v[3] = (bf16_t)u0.w;
  v[4] = (bf16_t)u1.x; v[5] = (bf16_t)u1.y; v[6] = (bf16_t)u1.z; v[7] = (bf16_t)u1.w;
  *(bf16x8*)d = v;
}

// ---------------- fully fused block kernel ----------------
// ROUND-13: round 12's remaining tax = B economics. 32-row tiles reuse each
// B-frag over only 2 row-frags -> 512B of B per MFMA; 8 blocks/CU stream
// 18MB of weights from L2; + the dbuf prefetch spilled (+74MB scratch).
// Fix: 64-ROW blocks, 4 waves (wave = col quarter x all 64 rows, acc[4][8]):
//   - B-bytes/MFMA 512 -> 256; B-load instructions and addr-VALU halved
//   - per-CU weight stream 18 -> 9 MB
//   - LDS = lX 64KB (pert, then x) + lH 16KB (h in 128-col EIGHTHS) = 80KB
//     -> still 2 blocks/CU (160KB) for cross-block phase overlap
//   - registers: B-only dbuf prefetch (no cross-step A prefetch): peak
//     acc 128 + bCur/bNxt 64 + af 16 ~ 208 < 256 -> no spill
//
// Phases: P0 pert->lX | P1 attn K=256 ->LN1-> x->lX | 8x { P2e h_e=gelu(
// x@W1 slice)->lH ; P3e acc3 += h_e@W2 slice } | P4 LN2 -> out.

// A-layout, 64-row tiles: 1KB windows; window = (k>>5)*4 + (row>>4);
// 16B slot = rr*4 + (chunk ^ ((rr>>1)&3)) (verified conflict-free).
__device__ __forceinline__ int alay(int row, int k) {
  const int rr = row & 15;
  const int c = (k >> 3) & 3;
  return ((k >> 5) * 4 + (row >> 4)) * 512 +
         (rr * 4 + (c ^ ((rr >> 1) & 3))) * 8 + (k & 7);
}

// B-dbuf-prefetch K-loop; A (LDS) read per-step (covered within step + co-block).
template <int STEPS, int NJ>
__device__ __forceinline__ void kloop(const bf16_t* __restrict__ lA_,
                                      const bf16_t* __restrict__ Bp,
                                      int g0, int SB, int soff,
                                      int fRd, int lane,
                                      f32x4 (&acc)[4][NJ]) {
  auto bfrag = [&](int j, int s) {
    return *(const bf16x8*)(Bp + ((size_t)((g0 + j) * SB + (soff + s)) * 64 + lane) * 8);
  };
  bf16x8 bCur[NJ], bNxt[NJ];
#pragma unroll
  for (int j = 0; j < NJ; ++j) bCur[j] = bfrag(j, 0);
#pragma unroll
  for (int s = 0; s < STEPS; ++s) {
    bf16x8 af[4];
#pragma unroll
    for (int i = 0; i < 4; ++i) af[i] = *(const bf16x8*)&lA_[(s * 4 + i) * 512 + fRd];
    if (s + 1 < STEPS) {
#pragma unroll
      for (int j = 0; j < NJ; ++j) bNxt[j] = bfrag(j, s + 1);  // full-step B prefetch
    }
    __builtin_amdgcn_s_setprio(1);
#pragma unroll
    for (int j = 0; j < NJ; ++j)
#pragma unroll
      for (int i = 0; i < 4; ++i)
        acc[i][j] = __builtin_amdgcn_mfma_f32_16x16x32_bf16(af[i], bCur[j], acc[i][j], 0, 0, 0);
    __builtin_amdgcn_s_setprio(0);
#pragma unroll
    for (int j = 0; j < NJ; ++j) bCur[j] = bNxt[j];  // SSA-renamed under unroll
  }
}

__global__ __launch_bounds__(256, 2) void fused_block(
    const float* __restrict__ pert, const bf16_t* __restrict__ Wc,
    const float* __restrict__ bcomb, const float* __restrict__ cell,
    const float* __restrict__ g1, const float* __restrict__ be1,
    const bf16_t* __restrict__ W1b, const float* __restrict__ b1,
    const bf16_t* __restrict__ W2b, const float* __restrict__ b2,
    const float* __restrict__ g2, const float* __restrict__ be2,
    float* __restrict__ out) {

  __shared__ __align__(16) bf16_t lX[64 * 512];   // 64 KB: pert (K<256), then x
  __shared__ __align__(16) bf16_t lH[64 * 128];   // 16 KB: h eighths
  // LN scratch aliased into lH (h dead at both LN points; pert lives in lX)
  float* rsP = (float*)lH;          // rs[4][64]  = 1 KB
  float* ssP = (float*)lH + 256;    // rss[4][64] = 1 KB

  const int t = threadIdx.x;
  const int m0 = blockIdx.x * 64;
  const int lane = t & 63;
  const int wc = t >> 6;          // wave 0..3 = col quarter; all 64 rows
  const int r = lane & 15;
  const int q = lane >> 4;
  const int qs = q ^ ((r >> 1) & 3);
  const int fRd = r * 32 + qs * 8;

  // ---- P0: stage pert (64 x 256 fp32 -> bf16, A-layout) into lX ----
#pragma unroll
  for (int u = 0; u < 8; ++u) {
    const int g = u * 256 + t;      // slot 0..2047
    const int row = g >> 5;
    const int c = g & 31;
    const float* src = pert + (size_t)(m0 + row) * 256 + c * 8;
    float4 u0 = *(const float4*)src;
    float4 u1 = *(const float4*)(src + 4);
    bf16x8 v;
    v[0] = (bf16_t)u0.x; v[1] = (bf16_t)u0.y; v[2] = (bf16_t)u0.z; v[3] = (bf16_t)u0.w;
    v[4] = (bf16_t)u1.x; v[5] = (bf16_t)u1.y; v[6] = (bf16_t)u1.z; v[7] = (bf16_t)u1.w;
    *(bf16x8*)&lX[alay(row, c * 8)] = v;
  }
  __syncthreads();

  // ---- P1: attn GEMM (K=256), wave cols [128wc,+128) ----
  {
    f32x4 acc1[4][8];
#pragma unroll
    for (int i = 0; i < 4; ++i)
#pragma unroll
      for (int j = 0; j < 8; ++j)
#pragma unroll
        for (int p = 0; p < 4; ++p) acc1[i][j][p] = 0.f;
    kloop<8, 8>(lX, Wc, 8 * wc, 8, 0, fRd, lane, acc1);

    float s_[4][4], ss_[4][4];
#pragma unroll
    for (int i = 0; i < 4; ++i)
#pragma unroll
      for (int p = 0; p < 4; ++p) { s_[i][p] = 0.f; ss_[i][p] = 0.f; }
    float bb[8];
#pragma unroll
    for (int j = 0; j < 8; ++j) bb[j] = bcomb[128 * wc + 16 * j + r];
#pragma unroll
    for (int i = 0; i < 4; ++i)
#pragma unroll
      for (int p = 0; p < 4; ++p) {
        const int rowl = 16 * i + 4 * q + p;
#pragma unroll
        for (int j = 0; j < 8; ++j) {
          const int col = 128 * wc + 16 * j + r;
          float v = acc1[i][j][p] + bb[j] + cell[(size_t)(m0 + rowl) * 512 + col];
          acc1[i][j][p] = v;
          s_[i][p] += v;
          ss_[i][p] += v * v;
        }
      }
#pragma unroll
    for (int m = 1; m <= 8; m <<= 1)
#pragma unroll
      for (int i = 0; i < 4; ++i)
#pragma unroll
        for (int p = 0; p < 4; ++p) {
          s_[i][p] += __shfl_xor(s_[i][p], m);
          ss_[i][p] += __shfl_xor(ss_[i][p], m);
        }
    __syncthreads();  // all waves past kloop before scratch write / x overwrite
    if (r == 0) {
#pragma unroll
      for (int i = 0; i < 4; ++i)
#pragma unroll
        for (int p = 0; p < 4; ++p) {
          const int rowl = 16 * i + 4 * q + p;
          rsP[wc * 64 + rowl] = s_[i][p];
          ssP[wc * 64 + rowl] = ss_[i][p];
        }
    }
    __syncthreads();
    float mu[4][4], inv[4][4];
#pragma unroll
    for (int i = 0; i < 4; ++i)
#pragma unroll
      for (int p = 0; p < 4; ++p) {
        const int rowl = 16 * i + 4 * q + p;
        float tS = rsP[rowl] + rsP[64 + rowl] + rsP[128 + rowl] + rsP[192 + rowl];
        float tQ = ssP[rowl] + ssP[64 + rowl] + ssP[128 + rowl] + ssP[192 + rowl];
        float m_ = tS * (1.0f / 512.0f);
        float v_ = tQ * (1.0f / 512.0f) - m_ * m_;
        mu[i][p] = m_;
        inv[i][p] = rsqrtf(v_ + 1e-5f);
      }
    float ga[8], be[8];
#pragma unroll
    for (int j = 0; j < 8; ++j) {
      ga[j] = g1[128 * wc + 16 * j + r];
      be[j] = be1[128 * wc + 16 * j + r];
    }
#pragma unroll
    for (int i = 0; i < 4; ++i)
#pragma unroll
      for (int p = 0; p < 4; ++p) {
        const int rowl = 16 * i + 4 * q + p;
#pragma unroll
        for (int j = 0; j < 8; ++j) {
          const int col = 128 * wc + 16 * j + r;
          float v = (acc1[i][j][p] - mu[i][p]) * inv[i][p] * ga[j] + be[j];
          lX[alay(rowl, col)] = (bf16_t)v;
        }
      }
  }
  __syncthreads();  // x fully resident (pert dead)

  // ---- FFN: eight 128-col h-eighths ----
  f32x4 acc3[4][8];
#pragma unroll
  for (int i = 0; i < 4; ++i)
#pragma unroll
    for (int j = 0; j < 8; ++j)
#pragma unroll
      for (int p = 0; p < 4; ++p) acc3[i][j][p] = 0.f;

  for (int e = 0; e < 8; ++e) {
    {
      f32x4 accq[4][2];
#pragma unroll
      for (int i = 0; i < 4; ++i)
#pragma unroll
        for (int j = 0; j < 2; ++j)
#pragma unroll
          for (int p = 0; p < 4; ++p) accq[i][j][p] = 0.f;
      // P2e: h_e = x @ W1[128e : +128]^T  (K=512; wave cols [32wc,+32))
      kloop<16, 2>(lX, W1b, 8 * e + 2 * wc, 16, 0, fRd, lane, accq);
      float bb1[2];
#pragma unroll
      for (int j = 0; j < 2; ++j) bb1[j] = b1[128 * e + 32 * wc + 16 * j + r];
#pragma unroll
      for (int i = 0; i < 4; ++i)
#pragma unroll
        for (int p = 0; p < 4; ++p) {
          const int rowl = 16 * i + 4 * q + p;
#pragma unroll
          for (int j = 0; j < 2; ++j) {
            const int col = 32 * wc + 16 * j + r;   // local col in eighth
            float v = accq[i][j][p] + bb1[j];
            float g = 0.5f * v * (1.0f + erff(v * 0.70710678118654752f));
            lH[alay(rowl, col)] = (bf16_t)g;
          }
        }
    }
    __syncthreads();  // h_e resident everywhere
    // P3e: acc3 += h_e @ W2[:, 128e : +128]^T  (K=128 -> steps 4e..4e+3)
    kloop<4, 8>(lH, W2b, 8 * wc, 32, 4 * e, fRd, lane, acc3);
    __syncthreads();  // all reads of h_e done before overwrite
  }

  // ---- P4: LN2(acc3 + b2 + x) -> fp32 out ----
  {
    float s_[4][4], ss_[4][4];
#pragma unroll
    for (int i = 0; i < 4; ++i)
#pragma unroll
      for (int p = 0; p < 4; ++p) { s_[i][p] = 0.f; ss_[i][p] = 0.f; }
    float bb2[8];
#pragma unroll
    for (int j = 0; j < 8; ++j) bb2[j] = b2[128 * wc + 16 * j + r];
#pragma unroll
    for (int i = 0; i < 4; ++i)
#pragma unroll
      for (int p = 0; p < 4; ++p) {
        const int rowl = 16 * i + 4 * q + p;
#pragma unroll
        for (int j = 0; j < 8; ++j) {
          const int col = 128 * wc + 16 * j + r;
          float v = acc3[i][j][p] + bb2[j] + (float)lX[alay(rowl, col)];
          acc3[i][j][p] = v;
          s_[i][p] += v;
          ss_[i][p] += v * v;
        }
      }
#pragma unroll
    for (int m = 1; m <= 8; m <<= 1)
#pragma unroll
      for (int i = 0; i < 4; ++i)
#pragma unroll
        for (int p = 0; p < 4; ++p) {
          s_[i][p] += __shfl_xor(s_[i][p], m);
          ss_[i][p] += __shfl_xor(ss_[i][p], m);
        }
    // lH readers (P3 e=7) done at loop-end barrier; scratch write safe
    if (r == 0) {
#pragma unroll
      for (int i = 0; i < 4; ++i)
#pragma unroll
        for (int p = 0; p < 4; ++p) {
          const int rowl = 16 * i + 4 * q + p;
          rsP[wc * 64 + rowl] = s_[i][p];
          ssP[wc * 64 + rowl] = ss_[i][p];
        }
    }
    __syncthreads();
    float mu[4][4], inv[4][4];
#pragma unroll
    for (int i = 0; i < 4; ++i)
#pragma unroll
      for (int p = 0; p < 4; ++p) {
        const int rowl = 16 * i + 4 * q + p;
        float tS = rsP[rowl] + rsP[64 + rowl] + rsP[128 + rowl] + rsP[192 + rowl];
        float tQ = ssP[rowl] + ssP[64 + rowl] + ssP[128 + rowl] + ssP[192 + rowl];
        float m_ = tS * (1.0f / 512.0f);
        float v_ = tQ * (1.0f / 512.0f) - m_ * m_;
        mu[i][p] = m_;
        inv[i][p] = rsqrtf(v_ + 1e-5f);
      }
    float ga[8], be[8];
#pragma unroll
    for (int j = 0; j < 8; ++j) {
      ga[j] = g2[128 * wc + 16 * j + r];
      be[j] = be2[128 * wc + 16 * j + r];
    }
#pragma unroll
    for (int i = 0; i < 4; ++i)
#pragma unroll
      for (int p = 0; p < 4; ++p) {
        const int rowl = 16 * i + 4 * q + p;
#pragma unroll
        for (int j = 0; j < 8; ++j) {
          const int col = 128 * wc + 16 * j + r;
          out[(size_t)(m0 + rowl) * 512 + col] =
              (acc3[i][j][p] - mu[i][p]) * inv[i][p] * ga[j] + be[j];
        }
      }
  }
}

extern "C" void kernel_launch(void* const* d_in, const int* in_sizes, int n_in,
                              void* d_out, int out_size, void* d_ws, size_t ws_size,
                              hipStream_t stream) {
  const float* cell = (const float*)d_in[0];
  const float* pert = (const float*)d_in[1];
  const float* Wp   = (const float*)d_in[2];
  const float* bp   = (const float*)d_in[3];
  // d_in[4..7] = Wq,bq,Wk,bk: dead (softmax over a single key == 1 -> attn = v)
  const float* Wv   = (const float*)d_in[8];
  const float* bv   = (const float*)d_in[9];
  const float* Wo   = (const float*)d_in[10];
  const float* bo   = (const float*)d_in[11];
  const float* g1   = (const float*)d_in[12];
  const float* be1  = (const float*)d_in[13];
  const float* g2   = (const float*)d_in[14];
  const float* be2  = (const float*)d_in[15];
  const float* W1   = (const float*)d_in[16];
  const float* b1   = (const float*)d_in[17];
  const float* W2   = (const float*)d_in[18];
  const float* b2   = (const float*)d_in[19];

  char* ws = (char*)d_ws;
  float*  Wvp   = (float*)(ws + 0);          // 512*256*4   = 524288
  float*  bvp   = (float*)(ws + 524288);     // 512*4 (pad) = 2048
  float*  bcomb = (float*)(ws + 526336);     // 512*4 (pad) = 2048
  bf16_t* Wc    = (bf16_t*)(ws + 528384);    // 512*256*2   = 262144 (packed)
  bf16_t* W1b   = (bf16_t*)(ws + 790528);    // 1024*512*2  = 1048576 (packed)
  bf16_t* W2b   = (bf16_t*)(ws + 1839104);   // 512*1024*2  = 1048576 (packed)
  (void)in_sizes; (void)n_in; (void)out_size; (void)ws_size;

  prep_wvp<<<512, 256, 0, stream>>>(Wv, Wp, bp, bv, Wvp, bvp);
  prep_wc<<<512, 256, 0, stream>>>(Wo, bo, Wvp, bvp, Wc, bcomb);
  prep_cast<<<512, 256, 0, stream>>>(W1, W2, W1b, W2b);

  fused_block<<<1024, 256, 0, stream>>>(pert, Wc, bcomb, cell, g1, be1,
                                        W1b, b1, W2b, b2, g2, be2,
                                        (float*)d_out);
}

// Round 14
// 598.851 us; speedup vs baseline: 1.0062x; 1.0062x over previous
//
#include <hip/hip_runtime.h>
#include <hip/hip_bf16.h>

typedef __bf16 bf16_t;
typedef __attribute__((ext_vector_type(8))) __bf16 bf16x8;
typedef __attribute__((ext_vector_type(4))) float f32x4;

// ---------------- prep kernels (rewritten fast, round 14) ----------------
// Old preps: 1 output/thread, 512-iter scalar loops, never measured; the
// bench's total-minus-fused has been a CONSTANT ~265us across rounds 9-13.
// New: float4 loads, 4 outputs/thread, wave-reduced bias vectors, and the
// independent cast kernel folded into prep_wc's launch (2 launches, not 3).

// Wvp(512x256) = Wv(512x512) @ Wp(512x256); bvp = Wv@bp + bv
__global__ __launch_bounds__(256) void prep_wvp_fast(
    const float* __restrict__ Wv, const float* __restrict__ Wp,
    const float* __restrict__ bp, const float* __restrict__ bv,
    float* __restrict__ Wvp, float* __restrict__ bvp) {
  const int t = threadIdx.x;
  const int rs = t >> 6;          // wave = row within block
  const int jg = t & 63;          // 4-col group
  const int i = blockIdx.x * 4 + rs;
  const float* wrow = Wv + (size_t)i * 512;
  float4 acc = {0.f, 0.f, 0.f, 0.f};
#pragma unroll 4
  for (int d = 0; d < 512; ++d) {
    const float s = wrow[d];
    const float4 p = *(const float4*)&Wp[d * 256 + jg * 4];
    acc.x += s * p.x; acc.y += s * p.y; acc.z += s * p.z; acc.w += s * p.w;
  }
  *(float4*)&Wvp[(size_t)i * 256 + jg * 4] = acc;
  // bvp[i]: lane jg sums d = 8jg..8jg+7, then 64-lane butterfly reduce
  float pb = 0.f;
#pragma unroll
  for (int u = 0; u < 8; ++u) { const int d = jg * 8 + u; pb += wrow[d] * bp[d]; }
#pragma unroll
  for (int m = 1; m <= 32; m <<= 1) pb += __shfl_xor(pb, m);
  if (jg == 0) bvp[i] = pb + bv[i];
}

// Packed-B layout (harness-verified rounds 4/7-13), N x K row-major source:
//   B[n][k] -> Bp[(((n>>4)*(K/32) + (k>>5))*64 + ((k>>3)&3)*16 + (n&15))*8 + (k&7)]
// blocks 0..127: Wc(512x256 packed) = Wo @ Wvp, bcomb = Wo@bvp + bo
// blocks 128..639: cast W1/W2 to bf16 packed (independent; folded launch)
__global__ __launch_bounds__(256) void prep_wc_cast(
    const float* __restrict__ Wo, const float* __restrict__ bo,
    const float* __restrict__ Wvp, const float* __restrict__ bvp,
    bf16_t* __restrict__ Wc, float* __restrict__ bcomb,
    const float* __restrict__ W1, const float* __restrict__ W2,
    bf16_t* __restrict__ W1b, bf16_t* __restrict__ W2b) {
  const int b = blockIdx.x;
  const int t = threadIdx.x;
  if (b < 128) {
    const int rs = t >> 6, jg = t & 63;
    const int o = b * 4 + rs;
    const float* worow = Wo + (size_t)o * 512;
    float4 acc = {0.f, 0.f, 0.f, 0.f};
#pragma unroll 4
    for (int i = 0; i < 512; ++i) {
      const float s = worow[i];
      const float4 p = *(const float4*)&Wvp[i * 256 + jg * 4];
      acc.x += s * p.x; acc.y += s * p.y; acc.z += s * p.z; acc.w += s * p.w;
    }
    const int g = o >> 4, rr = o & 15;
    const float av[4] = {acc.x, acc.y, acc.z, acc.w};
#pragma unroll
    for (int u = 0; u < 4; ++u) {
      const int k = jg * 4 + u;
      const int tt = k >> 5, q = (k >> 3) & 3, e = k & 7;
      Wc[((((size_t)g * 8 + tt) * 64) + q * 16 + rr) * 8 + e] = (bf16_t)av[u];  // S=8
    }
    float pb = 0.f;
#pragma unroll
    for (int u = 0; u < 8; ++u) { const int i = jg * 8 + u; pb += worow[i] * bvp[i]; }
#pragma unroll
    for (int m = 1; m <= 32; m <<= 1) pb += __shfl_xor(pb, m);
    if (jg == 0) bcomb[o] = pb + bo[o];
  } else {
    const int idx = ((b - 128) * 256 + t) * 8;
    const float* s;
    bf16_t* d;
    if (idx < 524288) {  // W1: K=512, S=16
      const int o = idx >> 9, k = idx & 511;
      const int g = o >> 4, rr = o & 15, tt = k >> 5, q = (k >> 3) & 3;
      s = W1 + idx;
      d = W1b + ((((size_t)g * 16 + tt) * 64) + q * 16 + rr) * 8;
    } else {             // W2: K=1024, S=32
      const int i2 = idx - 524288;
      const int o = i2 >> 10, k = i2 & 1023;
      const int g = o >> 4, rr = o & 15, tt = k >> 5, q = (k >> 3) & 3;
      s = W2 + i2;
      d = W2b + ((((size_t)g * 32 + tt) * 64) + q * 16 + rr) * 8;
    }
    float4 u0 = *(const float4*)s;
    float4 u1 = *(const float4*)(s + 4);
    bf16x8 v;
    v[0] = (bf16_t)u0.x; v[1] = (bf16_t)u0.y; v[2] = (bf16_t)u0.z; v[3] = (bf16_t)u0.w;
    v[4] = (bf16_t)u1.x; v[5] = (bf16_t)u1.y; v[6] = (bf16_t)u1.z; v[7] = (bf16_t)u1.w;
    *(bf16x8*)d = v;
  }
}

// ---------------- fully fused block kernel (byte-identical to round 12) ----------------
// 32-row blocks, 256 thr / 4 waves, 2 blocks/CU; full-step register pipeline
// (bNxt/aNxt prefetch during MFMAs). Measured round 12: 309us, MfmaUtil 21.7.
// This round it is the CONTROL -- the experiment is the preps.

// A-layout for 32-row tiles: 16-row windows of 1KB; window = (k>>5)*2+(row>>4);
// 16B slot within window = rr*4 + (chunk ^ ((rr>>1)&3)) (verified conflict-free).
__device__ __forceinline__ int alay(int row, int k) {
  const int rr = row & 15;
  const int c = (k >> 3) & 3;
  return ((k >> 5) * 2 + (row >> 4)) * 512 +
         (rr * 4 + (c ^ ((rr >> 1) & 3))) * 8 + (k & 7);
}

template <int STEPS, int NJ>
__device__ __forceinline__ void kloop(const bf16_t* __restrict__ lA_,
                                      const bf16_t* __restrict__ Bp,
                                      int g0, int SB, int soff,
                                      int fRd, int lane,
                                      f32x4 (&acc)[2][NJ]) {
  auto bfrag = [&](int j, int s) {
    return *(const bf16x8*)(Bp + ((size_t)((g0 + j) * SB + (soff + s)) * 64 + lane) * 8);
  };
  auto afrag = [&](int i, int s) {
    return *(const bf16x8*)&lA_[(s * 2 + i) * 512 + fRd];
  };
  bf16x8 bCur[NJ], bNxt[NJ], aCur[2], aNxt[2];
#pragma unroll
  for (int j = 0; j < NJ; ++j) bCur[j] = bfrag(j, 0);
#pragma unroll
  for (int i = 0; i < 2; ++i) aCur[i] = afrag(i, 0);
#pragma unroll
  for (int s = 0; s < STEPS; ++s) {
    if (s + 1 < STEPS) {
#pragma unroll
      for (int j = 0; j < NJ; ++j) bNxt[j] = bfrag(j, s + 1);
#pragma unroll
      for (int i = 0; i < 2; ++i) aNxt[i] = afrag(i, s + 1);
    }
    __builtin_amdgcn_s_setprio(1);
#pragma unroll
    for (int j = 0; j < NJ; ++j)
#pragma unroll
      for (int i = 0; i < 2; ++i)
        acc[i][j] = __builtin_amdgcn_mfma_f32_16x16x32_bf16(aCur[i], bCur[j], acc[i][j], 0, 0, 0);
    __builtin_amdgcn_s_setprio(0);
#pragma unroll
    for (int j = 0; j < NJ; ++j) bCur[j] = bNxt[j];
#pragma unroll
    for (int i = 0; i < 2; ++i) aCur[i] = aNxt[i];
  }
}

__global__ __launch_bounds__(256, 2) void fused_block(
    const float* __restrict__ pert, const bf16_t* __restrict__ Wc,
    const float* __restrict__ bcomb, const float* __restrict__ cell,
    const float* __restrict__ g1, const float* __restrict__ be1,
    const bf16_t* __restrict__ W1b, const float* __restrict__ b1,
    const bf16_t* __restrict__ W2b, const float* __restrict__ b2,
    const float* __restrict__ g2, const float* __restrict__ be2,
    float* __restrict__ out) {

  __shared__ __align__(16) bf16_t lX[32 * 512];   // 32 KB: x (A-layout, K=512)
  __shared__ __align__(16) bf16_t lH[32 * 256];   // 16 KB: pert, then h quarters
  float* rsP = (float*)lH;          // rs[4][32]  = 512 B (aliased; h/pert dead)
  float* ssP = (float*)lH + 128;    // rss[4][32] = 512 B

  const int t = threadIdx.x;
  const int m0 = blockIdx.x * 32;
  const int lane = t & 63;
  const int wc = t >> 6;          // wave 0..3 = col quarter; all 32 rows
  const int r = lane & 15;
  const int q = lane >> 4;
  const int qs = q ^ ((r >> 1) & 3);
  const int fRd = r * 32 + qs * 8;

  // ---- P0: stage pert (32 x 256 fp32 -> bf16, A-layout) into lH ----
#pragma unroll
  for (int u = 0; u < 4; ++u) {
    const int g = u * 256 + t;      // slot 0..1023
    const int row = g >> 5;
    const int c = g & 31;
    const float* src = pert + (size_t)(m0 + row) * 256 + c * 8;
    float4 u0 = *(const float4*)src;
    float4 u1 = *(const float4*)(src + 4);
    bf16x8 v;
    v[0] = (bf16_t)u0.x; v[1] = (bf16_t)u0.y; v[2] = (bf16_t)u0.z; v[3] = (bf16_t)u0.w;
    v[4] = (bf16_t)u1.x; v[5] = (bf16_t)u1.y; v[6] = (bf16_t)u1.z; v[7] = (bf16_t)u1.w;
    *(bf16x8*)&lH[alay(row, c * 8)] = v;
  }
  __syncthreads();

  // ---- P1: attn GEMM (K=256), wave cols [128wc,+128) ----
  {
    f32x4 acc1[2][8];
#pragma unroll
    for (int i = 0; i < 2; ++i)
#pragma unroll
      for (int j = 0; j < 8; ++j)
#pragma unroll
        for (int p = 0; p < 4; ++p) acc1[i][j][p] = 0.f;
    kloop<8, 8>(lH, Wc, 8 * wc, 8, 0, fRd, lane, acc1);

    float s_[2][4], ss_[2][4];
#pragma unroll
    for (int i = 0; i < 2; ++i)
#pragma unroll
      for (int p = 0; p < 4; ++p) { s_[i][p] = 0.f; ss_[i][p] = 0.f; }
    float bb[8];
#pragma unroll
    for (int j = 0; j < 8; ++j) bb[j] = bcomb[128 * wc + 16 * j + r];
#pragma unroll
    for (int i = 0; i < 2; ++i)
#pragma unroll
      for (int p = 0; p < 4; ++p) {
        const int rowl = 16 * i + 4 * q + p;
#pragma unroll
        for (int j = 0; j < 8; ++j) {
          const int col = 128 * wc + 16 * j + r;
          float v = acc1[i][j][p] + bb[j] + cell[(size_t)(m0 + rowl) * 512 + col];
          acc1[i][j][p] = v;
          s_[i][p] += v;
          ss_[i][p] += v * v;
        }
      }
#pragma unroll
    for (int m = 1; m <= 8; m <<= 1)
#pragma unroll
      for (int i = 0; i < 2; ++i)
#pragma unroll
        for (int p = 0; p < 4; ++p) {
          s_[i][p] += __shfl_xor(s_[i][p], m);
          ss_[i][p] += __shfl_xor(ss_[i][p], m);
        }
    __syncthreads();  // all waves past kloop(lH) before aliased scratch write
    if (r == 0) {
#pragma unroll
      for (int i = 0; i < 2; ++i)
#pragma unroll
        for (int p = 0; p < 4; ++p) {
          const int rowl = 16 * i + 4 * q + p;
          rsP[wc * 32 + rowl] = s_[i][p];
          ssP[wc * 32 + rowl] = ss_[i][p];
        }
    }
    __syncthreads();
    float mu[2][4], inv[2][4];
#pragma unroll
    for (int i = 0; i < 2; ++i)
#pragma unroll
      for (int p = 0; p < 4; ++p) {
        const int rowl = 16 * i + 4 * q + p;
        float tS = rsP[rowl] + rsP[32 + rowl] + rsP[64 + rowl] + rsP[96 + rowl];
        float tQ = ssP[rowl] + ssP[32 + rowl] + ssP[64 + rowl] + ssP[96 + rowl];
        float m_ = tS * (1.0f / 512.0f);
        float v_ = tQ * (1.0f / 512.0f) - m_ * m_;
        mu[i][p] = m_;
        inv[i][p] = rsqrtf(v_ + 1e-5f);
      }
    float ga[8], be[8];
#pragma unroll
    for (int j = 0; j < 8; ++j) {
      ga[j] = g1[128 * wc + 16 * j + r];
      be[j] = be1[128 * wc + 16 * j + r];
    }
#pragma unroll
    for (int i = 0; i < 2; ++i)
#pragma unroll
      for (int p = 0; p < 4; ++p) {
        const int rowl = 16 * i + 4 * q + p;
#pragma unroll
        for (int j = 0; j < 8; ++j) {
          const int col = 128 * wc + 16 * j + r;
          float v = (acc1[i][j][p] - mu[i][p]) * inv[i][p] * ga[j] + be[j];
          lX[alay(rowl, col)] = (bf16_t)v;
        }
      }
  }
  __syncthreads();  // x resident; lH (pert + scratch) dead

  // ---- FFN: four 256-col h-quarters ----
  f32x4 acc3[2][8];
#pragma unroll
  for (int i = 0; i < 2; ++i)
#pragma unroll
    for (int j = 0; j < 8; ++j)
#pragma unroll
      for (int p = 0; p < 4; ++p) acc3[i][j][p] = 0.f;

  for (int qh = 0; qh < 4; ++qh) {
    {
      f32x4 accq[2][4];
#pragma unroll
      for (int i = 0; i < 2; ++i)
#pragma unroll
        for (int j = 0; j < 4; ++j)
#pragma unroll
          for (int p = 0; p < 4; ++p) accq[i][j][p] = 0.f;
      // P2q: h_q = x @ W1[256qh : +256]^T  (K=512; wave cols [64wc,+64))
      kloop<16, 4>(lX, W1b, 16 * qh + 4 * wc, 16, 0, fRd, lane, accq);
      float bb1[4];
#pragma unroll
      for (int j = 0; j < 4; ++j) bb1[j] = b1[256 * qh + 64 * wc + 16 * j + r];
#pragma unroll
      for (int i = 0; i < 2; ++i)
#pragma unroll
        for (int p = 0; p < 4; ++p) {
          const int rowl = 16 * i + 4 * q + p;
#pragma unroll
          for (int j = 0; j < 4; ++j) {
            const int col = 64 * wc + 16 * j + r;
            float v = accq[i][j][p] + bb1[j];
            float g = 0.5f * v * (1.0f + erff(v * 0.70710678118654752f));
            lH[alay(rowl, col)] = (bf16_t)g;
          }
        }
    }
    __syncthreads();  // h_q resident everywhere
    // P3q: acc3 += h_q @ W2[:, 256qh : +256]^T  (K=256)
    kloop<8, 8>(lH, W2b, 8 * wc, 32, 8 * qh, fRd, lane, acc3);
    __syncthreads();  // all reads of h_q done before overwrite
  }

  // ---- P4: LN2(acc3 + b2 + x) -> fp32 out ----
  {
    float s_[2][4], ss_[2][4];
#pragma unroll
    for (int i = 0; i < 2; ++i)
#pragma unroll
      for (int p = 0; p < 4; ++p) { s_[i][p] = 0.f; ss_[i][p] = 0.f; }
    float bb2[8];
#pragma unroll
    for (int j = 0; j < 8; ++j) bb2[j] = b2[128 * wc + 16 * j + r];
#pragma unroll
    for (int i = 0; i < 2; ++i)
#pragma unroll
      for (int p = 0; p < 4; ++p) {
        const int rowl = 16 * i + 4 * q + p;
#pragma unroll
        for (int j = 0; j < 8; ++j) {
          const int col = 128 * wc + 16 * j + r;
          float v = acc3[i][j][p] + bb2[j] + (float)lX[alay(rowl, col)];
          acc3[i][j][p] = v;
          s_[i][p] += v;
          ss_[i][p] += v * v;
        }
      }
#pragma unroll
    for (int m = 1; m <= 8; m <<= 1)
#pragma unroll
      for (int i = 0; i < 2; ++i)
#pragma unroll
        for (int p = 0; p < 4; ++p) {
          s_[i][p] += __shfl_xor(s_[i][p], m);
          ss_[i][p] += __shfl_xor(ss_[i][p], m);
        }
    if (r == 0) {
#pragma unroll
      for (int i = 0; i < 2; ++i)
#pragma unroll
        for (int p = 0; p < 4; ++p) {
          const int rowl = 16 * i + 4 * q + p;
          rsP[wc * 32 + rowl] = s_[i][p];
          ssP[wc * 32 + rowl] = ss_[i][p];
        }
    }
    __syncthreads();
    float mu[2][4], inv[2][4];
#pragma unroll
    for (int i = 0; i < 2; ++i)
#pragma unroll
      for (int p = 0; p < 4; ++p) {
        const int rowl = 16 * i + 4 * q + p;
        float tS = rsP[rowl] + rsP[32 + rowl] + rsP[64 + rowl] + rsP[96 + rowl];
        float tQ = ssP[rowl] + ssP[32 + rowl] + ssP[64 + rowl] + ssP[96 + rowl];
        float m_ = tS * (1.0f / 512.0f);
        float v_ = tQ * (1.0f / 512.0f) - m_ * m_;
        mu[i][p] = m_;
        inv[i][p] = rsqrtf(v_ + 1e-5f);
      }
    float ga[8], be[8];
#pragma unroll
    for (int j = 0; j < 8; ++j) {
      ga[j] = g2[128 * wc + 16 * j + r];
      be[j] = be2[128 * wc + 16 * j + r];
    }
#pragma unroll
    for (int i = 0; i < 2; ++i)
#pragma unroll
      for (int p = 0; p < 4; ++p) {
        const int rowl = 16 * i + 4 * q + p;
#pragma unroll
        for (int j = 0; j < 8; ++j) {
          const int col = 128 * wc + 16 * j + r;
          out[(size_t)(m0 + rowl) * 512 + col] =
              (acc3[i][j][p] - mu[i][p]) * inv[i][p] * ga[j] + be[j];
        }
      }
  }
}

extern "C" void kernel_launch(void* const* d_in, const int* in_sizes, int n_in,
                              void* d_out, int out_size, void* d_ws, size_t ws_size,
                              hipStream_t stream) {
  const float* cell = (const float*)d_in[0];
  const float* pert = (const float*)d_in[1];
  const float* Wp   = (const float*)d_in[2];
  const float* bp   = (const float*)d_in[3];
  // d_in[4..7] = Wq,bq,Wk,bk: dead (softmax over a single key == 1 -> attn = v)
  const float* Wv   = (const float*)d_in[8];
  const float* bv   = (const float*)d_in[9];
  const float* Wo   = (const float*)d_in[10];
  const float* bo   = (const float*)d_in[11];
  const float* g1   = (const float*)d_in[12];
  const float* be1  = (const float*)d_in[13];
  const float* g2   = (const float*)d_in[14];
  const float* be2  = (const float*)d_in[15];
  const float* W1   = (const float*)d_in[16];
  const float* b1   = (const float*)d_in[17];
  const float* W2   = (const float*)d_in[18];
  const float* b2   = (const float*)d_in[19];

  char* ws = (char*)d_ws;
  float*  Wvp   = (float*)(ws + 0);          // 512*256*4   = 524288
  float*  bvp   = (float*)(ws + 524288);     // 512*4 (pad) = 2048
  float*  bcomb = (float*)(ws + 526336);     // 512*4 (pad) = 2048
  bf16_t* Wc    = (bf16_t*)(ws + 528384);    // 512*256*2   = 262144 (packed)
  bf16_t* W1b   = (bf16_t*)(ws + 790528);    // 1024*512*2  = 1048576 (packed)
  bf16_t* W2b   = (bf16_t*)(ws + 1839104);   // 512*1024*2  = 1048576 (packed)
  (void)in_sizes; (void)n_in; (void)out_size; (void)ws_size;

  prep_wvp_fast<<<128, 256, 0, stream>>>(Wv, Wp, bp, bv, Wvp, bvp);
  prep_wc_cast<<<640, 256, 0, stream>>>(Wo, bo, Wvp, bvp, Wc, bcomb,
                                        W1, W2, W1b, W2b);

  fused_block<<<2048, 256, 0, stream>>>(pert, Wc, bcomb, cell, g1, be1,
                                        W1b, b1, W2b, b2, g2, be2,
                                        (float*)d_out);
}